// Round 1
// baseline (514.100 us; speedup 1.0000x reference)
//
#include <hip/hip_runtime.h>
#include <hip/hip_bf16.h>
#include <cstdint>
#include <cstddef>

typedef __bf16 bf16x8 __attribute__((ext_vector_type(8)));
typedef float f32x4 __attribute__((ext_vector_type(4)));

#define MOD_SCALE 1.4731391e-02f   // 1/sqrt(512*9)
#define EPSF 1e-8f

// ---------------------------------------------------------------------------
// K1: s[b][i] = dot(style[b], mod_w[i]) + mod_b[i]
// ---------------------------------------------------------------------------
__global__ __launch_bounds__(512) void k_style(
    const float* __restrict__ style, const float* __restrict__ mod_w,
    const float* __restrict__ mod_b, float* __restrict__ s)
{
  __shared__ float st[512];
  const int b = blockIdx.x, i = threadIdx.x;
  st[i] = style[b*512 + i];
  __syncthreads();
  const float4* mw = (const float4*)(mod_w + (size_t)i*512);
  float acc = 0.f;
  #pragma unroll 8
  for (int j = 0; j < 128; ++j) {
    float4 v = mw[j];
    acc += v.x*st[4*j] + v.y*st[4*j+1] + v.z*st[4*j+2] + v.w*st[4*j+3];
  }
  s[b*512 + i] = acc + mod_b[i];
}

// ---------------------------------------------------------------------------
// K2: w2[o][i] = sum_kk weight^2 ; Wb[kk][o][i] = bf16(SCALE*weight)
// ---------------------------------------------------------------------------
__global__ __launch_bounds__(256) void k_weight(
    const float* __restrict__ weight, float* __restrict__ w2,
    __hip_bfloat16* __restrict__ Wb)
{
  const int o = blockIdx.x, t = threadIdx.x;
  #pragma unroll
  for (int h = 0; h < 2; ++h) {
    const int i = t + h*256;
    const float* wp = weight + ((size_t)o*512 + i)*9;
    float sq = 0.f;
    #pragma unroll
    for (int kk = 0; kk < 9; ++kk) {
      float v = wp[kk];
      sq += v*v;
      Wb[((size_t)kk*512 + o)*512 + i] = __float2bfloat16(v * MOD_SCALE);
    }
    w2[(size_t)o*512 + i] = sq;
  }
}

// ---------------------------------------------------------------------------
// K2b: demod[b][o] = rsqrt(SCALE^2 * sum_i s[b][i]^2 * w2[o][i] + eps)
// ---------------------------------------------------------------------------
__global__ __launch_bounds__(256) void k_demod(
    const float* __restrict__ s, const float* __restrict__ w2,
    float* __restrict__ demod)
{
  __shared__ float s2[512];
  const int b = blockIdx.x, t = threadIdx.x;
  {
    float a = s[b*512 + t];        s2[t]     = a*a;
    float c = s[b*512 + t + 256];  s2[t+256] = c*c;
  }
  __syncthreads();
  #pragma unroll
  for (int h = 0; h < 2; ++h) {
    const int o = t + h*256;
    const float4* wp = (const float4*)(w2 + (size_t)o*512);
    float acc = 0.f;
    #pragma unroll 8
    for (int j = 0; j < 128; ++j) {
      float4 v = wp[j];
      acc += v.x*s2[4*j] + v.y*s2[4*j+1] + v.z*s2[4*j+2] + v.w*s2[4*j+3];
    }
    demod[b*512 + o] = rsqrtf(MOD_SCALE*MOD_SCALE*acc + EPSF);
  }
}

// ---------------------------------------------------------------------------
// K3: Xm[b][py][px][i] = bf16(s[b][i] * x[b][i][py-1][px-1])  (interior only;
//     halo pre-zeroed by memset).  NCHW fp32 -> padded NHWC bf16 via LDS.
// One block: 32 channels x 64 x, for one (b, y).
// ---------------------------------------------------------------------------
__global__ __launch_bounds__(256) void k_xm(
    const float* __restrict__ x, const float* __restrict__ s,
    __hip_bfloat16* __restrict__ Xm)
{
  __shared__ __hip_bfloat16 T[64][40];   // [x][i], padded to keep 16B-aligned reads
  const int bid = blockIdx.x;
  const int cb = bid & 15, y = (bid >> 4) & 63, b = bid >> 10;
  const int ic0 = cb*32;
  const int t = threadIdx.x;
  const int i = t >> 3, x0 = (t & 7)*8;
  const float sv = s[b*512 + ic0 + i];
  const float4* xp = (const float4*)(x + (size_t)(b*512 + ic0 + i)*4096 + y*64 + x0);
  float4 v0 = xp[0], v1 = xp[1];
  float vals[8] = {v0.x, v0.y, v0.z, v0.w, v1.x, v1.y, v1.z, v1.w};
  #pragma unroll
  for (int j = 0; j < 8; ++j) T[x0+j][i] = __float2bfloat16(vals[j]*sv);
  __syncthreads();
  const int p = t >> 2, c = (t & 3)*8;
  __hip_bfloat16* dst = Xm + (((size_t)(b*66 + (y+1))*66 + (p+1))*512 + ic0 + c);
  *(float4*)dst = *(const float4*)&T[p][c];
}

// ---------------------------------------------------------------------------
// K4: conv as 9 fused GEMMs (tap-outer), m97 structure.
// C[o, n] += Wb[kk][o][:] . Xm[b][y(n)+dy][x(n)+dx][:]  over 16 chunks of 32 ch
// Block: 128 o x 128 spatial (2 image rows), 4 waves, 4x4 16x16x32 frags/wave.
// ---------------------------------------------------------------------------
__global__ __launch_bounds__(256, 2) void k_conv(
    const __hip_bfloat16* __restrict__ Wb,   // [9][512][512]
    const __hip_bfloat16* __restrict__ Xm,   // [16][66][66][512]
    const float* __restrict__ demod,         // [16][512]
    float* __restrict__ out)                 // [16][512][64][64]
{
  __shared__ __hip_bfloat16 As[128*32];
  __shared__ __hip_bfloat16 Bs[128*32];

  const int bid = blockIdx.x;
  const int mt = bid & 3, nt = (bid >> 2) & 31, b = bid >> 7;
  const int o0 = mt*128, y0 = nt*2;

  const int tid = threadIdx.x;
  const int lane = tid & 63;
  const int w = tid >> 6;
  const int wr = w >> 1, wc = w & 1;
  const int frow = lane & 15;
  const int fk = (lane >> 4)*8;

  f32x4 acc[4][4] = {};

  for (int kk = 0; kk < 9; ++kk) {
    const int dy = kk/3 - 1, dx = kk % 3 - 1;
    for (int ic0 = 0; ic0 < 512; ic0 += 32) {
      __syncthreads();
      #pragma unroll
      for (int it = 0; it < 2; ++it) {
        const int off = tid*16 + it*4096;       // byte offset in tile
        const int row = off >> 6, col = off & 63;
        // A: Wb[kk][o0+row][ic0 .. ic0+32), 16B per lane
        const char* srcA = (const char*)Wb
            + ((size_t)(kk*512 + o0 + row)*512 + ic0)*2 + col;
        __builtin_amdgcn_global_load_lds(
            (__attribute__((address_space(1))) void*)srcA,
            (__attribute__((address_space(3))) void*)((char*)As + w*1024 + it*4096),
            16, 0, 0);
        // B: Xm[b][y0+(row>>6)+dy+1][(row&63)+dx+1][ic0 .. ic0+32)
        const int py = y0 + (row >> 6) + dy + 1;
        const int px = (row & 63) + dx + 1;
        const char* srcB = (const char*)Xm
            + ((size_t)((b*66 + py)*66 + px)*512 + ic0)*2 + col;
        __builtin_amdgcn_global_load_lds(
            (__attribute__((address_space(1))) void*)srcB,
            (__attribute__((address_space(3))) void*)((char*)Bs + w*1024 + it*4096),
            16, 0, 0);
      }
      asm volatile("s_waitcnt vmcnt(0)" ::: "memory");
      __syncthreads();

      bf16x8 af[4], bfr[4];
      #pragma unroll
      for (int m = 0; m < 4; ++m)
        af[m] = *(const bf16x8*)&As[(wr*64 + m*16 + frow)*32 + fk];
      #pragma unroll
      for (int n = 0; n < 4; ++n)
        bfr[n] = *(const bf16x8*)&Bs[(wc*64 + n*16 + frow)*32 + fk];
      #pragma unroll
      for (int m = 0; m < 4; ++m)
        #pragma unroll
        for (int n = 0; n < 4; ++n)
          acc[m][n] = __builtin_amdgcn_mfma_f32_16x16x32_bf16(af[m], bfr[n], acc[m][n], 0, 0, 0);
    }
  }

  // epilogue: scale by demod[b][o], write NCHW fp32
  #pragma unroll
  for (int m = 0; m < 4; ++m) {
    const int ob = o0 + wr*64 + m*16 + (lane >> 4)*4;
    float dmv[4];
    #pragma unroll
    for (int r = 0; r < 4; ++r) dmv[r] = demod[b*512 + ob + r];
    #pragma unroll
    for (int n = 0; n < 4; ++n) {
      const int ccol = wc*64 + n*16 + (lane & 15);
      const int y = y0 + (ccol >> 6), xx = ccol & 63;
      #pragma unroll
      for (int r = 0; r < 4; ++r) {
        out[(size_t)(b*512 + ob + r)*4096 + y*64 + xx] = acc[m][n][r]*dmv[r];
      }
    }
  }
}

// ---------------------------------------------------------------------------
extern "C" void kernel_launch(void* const* d_in, const int* in_sizes, int n_in,
                              void* d_out, int out_size, void* d_ws, size_t ws_size,
                              hipStream_t stream)
{
  const float* x      = (const float*)d_in[0];
  const float* style  = (const float*)d_in[1];
  const float* weight = (const float*)d_in[2];
  const float* mod_w  = (const float*)d_in[3];
  const float* mod_b  = (const float*)d_in[4];
  float* out = (float*)d_out;

  char* ws = (char*)d_ws;
  float* s            = (float*)(ws);                  //  32 KB  [16][512]
  float* demod        = (float*)(ws + 32768);          //  32 KB  [16][512]
  float* w2           = (float*)(ws + 65536);          //   1 MB  [512][512]
  __hip_bfloat16* Wb  = (__hip_bfloat16*)(ws + 1114112);   // 4.5 MB [9][512][512]
  __hip_bfloat16* Xm  = (__hip_bfloat16*)(ws + 5832704);   // 71.4 MB [16][66][66][512]

  // zero the padded halo of Xm (and everything else; interior overwritten by k_xm)
  hipMemsetAsync(Xm, 0, (size_t)16*66*66*512*2, stream);

  k_style <<<16,    512, 0, stream>>>(style, mod_w, mod_b, s);
  k_weight<<<512,   256, 0, stream>>>(weight, w2, Wb);
  k_demod <<<16,    256, 0, stream>>>(s, w2, demod);
  k_xm    <<<16384, 256, 0, stream>>>(x, s, Xm);
  k_conv  <<<2048,  256, 0, stream>>>(Wb, Xm, demod, out);
}

// Round 2
// 433.101 us; speedup vs baseline: 1.1870x; 1.1870x over previous
//
#include <hip/hip_runtime.h>
#include <hip/hip_bf16.h>
#include <cstdint>
#include <cstddef>

typedef __bf16 bf16x8 __attribute__((ext_vector_type(8)));
typedef float f32x4 __attribute__((ext_vector_type(4)));

#define MOD_SCALE 1.4731391e-02f   // 1/sqrt(512*9)
#define EPSF 1e-8f

// ---------------------------------------------------------------------------
// K1: s[b][i] = dot(style[b], mod_w[i]) + mod_b[i]
// ---------------------------------------------------------------------------
__global__ __launch_bounds__(512) void k_style(
    const float* __restrict__ style, const float* __restrict__ mod_w,
    const float* __restrict__ mod_b, float* __restrict__ s)
{
  __shared__ float st[512];
  const int b = blockIdx.x, i = threadIdx.x;
  st[i] = style[b*512 + i];
  __syncthreads();
  const float4* mw = (const float4*)(mod_w + (size_t)i*512);
  float acc = 0.f;
  #pragma unroll 8
  for (int j = 0; j < 128; ++j) {
    float4 v = mw[j];
    acc += v.x*st[4*j] + v.y*st[4*j+1] + v.z*st[4*j+2] + v.w*st[4*j+3];
  }
  s[b*512 + i] = acc + mod_b[i];
}

// ---------------------------------------------------------------------------
// K2: w2[o][i] = sum_kk weight^2 ; Wb[kk][o][i] = bf16(SCALE*weight)
// ---------------------------------------------------------------------------
__global__ __launch_bounds__(256) void k_weight(
    const float* __restrict__ weight, float* __restrict__ w2,
    __hip_bfloat16* __restrict__ Wb)
{
  const int o = blockIdx.x, t = threadIdx.x;
  #pragma unroll
  for (int h = 0; h < 2; ++h) {
    const int i = t + h*256;
    const float* wp = weight + ((size_t)o*512 + i)*9;
    float sq = 0.f;
    #pragma unroll
    for (int kk = 0; kk < 9; ++kk) {
      float v = wp[kk];
      sq += v*v;
      Wb[((size_t)kk*512 + o)*512 + i] = __float2bfloat16(v * MOD_SCALE);
    }
    w2[(size_t)o*512 + i] = sq;
  }
}

// ---------------------------------------------------------------------------
// K2b: demod[b][o] = rsqrt(SCALE^2 * sum_i s[b][i]^2 * w2[o][i] + eps)
// ---------------------------------------------------------------------------
__global__ __launch_bounds__(256) void k_demod(
    const float* __restrict__ s, const float* __restrict__ w2,
    float* __restrict__ demod)
{
  __shared__ float s2[512];
  const int b = blockIdx.x, t = threadIdx.x;
  {
    float a = s[b*512 + t];        s2[t]     = a*a;
    float c = s[b*512 + t + 256];  s2[t+256] = c*c;
  }
  __syncthreads();
  #pragma unroll
  for (int h = 0; h < 2; ++h) {
    const int o = t + h*256;
    const float4* wp = (const float4*)(w2 + (size_t)o*512);
    float acc = 0.f;
    #pragma unroll 8
    for (int j = 0; j < 128; ++j) {
      float4 v = wp[j];
      acc += v.x*s2[4*j] + v.y*s2[4*j+1] + v.z*s2[4*j+2] + v.w*s2[4*j+3];
    }
    demod[b*512 + o] = rsqrtf(MOD_SCALE*MOD_SCALE*acc + EPSF);
  }
}

// ---------------------------------------------------------------------------
// K3: Xm[b][py][px][i] = bf16(s[b][i] * x[b][i][py-1][px-1])  (interior only;
//     halo pre-zeroed by memset).  NCHW fp32 -> padded NHWC bf16 via LDS.
// ---------------------------------------------------------------------------
__global__ __launch_bounds__(256) void k_xm(
    const float* __restrict__ x, const float* __restrict__ s,
    __hip_bfloat16* __restrict__ Xm)
{
  __shared__ __hip_bfloat16 T[64][40];
  const int bid = blockIdx.x;
  const int cb = bid & 15, y = (bid >> 4) & 63, b = bid >> 10;
  const int ic0 = cb*32;
  const int t = threadIdx.x;
  const int i = t >> 3, x0 = (t & 7)*8;
  const float sv = s[b*512 + ic0 + i];
  const float4* xp = (const float4*)(x + (size_t)(b*512 + ic0 + i)*4096 + y*64 + x0);
  float4 v0 = xp[0], v1 = xp[1];
  float vals[8] = {v0.x, v0.y, v0.z, v0.w, v1.x, v1.y, v1.z, v1.w};
  #pragma unroll
  for (int j = 0; j < 8; ++j) T[x0+j][i] = __float2bfloat16(vals[j]*sv);
  __syncthreads();
  const int p = t >> 2, c = (t & 3)*8;
  __hip_bfloat16* dst = Xm + (((size_t)(b*66 + (y+1))*66 + (p+1))*512 + ic0 + c);
  *(float4*)dst = *(const float4*)&T[p][c];
}

// ---------------------------------------------------------------------------
// K4: conv as implicit GEMM, 256x256 8-phase schedule (T1+T2+T3+T4+T5).
// M=512 (o, 2 tiles), N=4096 (spatial, 16 tiles of 4 image rows), K=72x64.
// 8 waves (2M x 4N, interleaved), wave tile 128x64, acc[8][4] f32x4.
// LDS 128 KiB: [buf][A/B][256 rows][64ch], col byte ^= ((row&7)<<4) swizzle.
// ---------------------------------------------------------------------------
#define VMC(n) asm volatile("s_waitcnt vmcnt(" #n ")" ::: "memory")

__global__ __launch_bounds__(512, 2) void k_conv(
    const __hip_bfloat16* __restrict__ Wb,   // [9][512][512]
    const __hip_bfloat16* __restrict__ Xm,   // [16][66][66][512]
    const float* __restrict__ demod,         // [16][512]
    float* __restrict__ out)                 // [16][512][64][64]
{
  __shared__ __hip_bfloat16 lds[2][2][16384];   // [buf][A=0/B=1][256*64]

  const int orig = blockIdx.x;
  const int swz = (orig & 7)*64 + (orig >> 3);   // bijective XCD swizzle (512%8==0)
  const int b  = swz >> 5;
  const int nt = (swz & 31) >> 1;
  const int mt = swz & 1;
  const int o0 = mt*256, y0 = nt*4;

  const int tid = threadIdx.x;
  const int l = tid & 63;
  const int w = tid >> 6;
  const int wm = w >> 2;       // 0..1
  const int wn = w & 3;        // 0..3

  // staging per-thread constants (linear LDS dest; inverse-swizzled source)
  const int srow = tid >> 3;                                  // 0..63
  const int scol = ((tid & 7) << 4) ^ ((srow & 7) << 4);      // src col byte
  const char* WbC = (const char*)Wb;
  const char* XmC = (const char*)Xm;

  // frag-read per-lane constants (swizzled ds_read col)
  const int frow = l & 15;
  const int fk0 = ((l >> 4) << 4) ^ ((l & 7) << 4);
  const int fk1 = fk0 ^ 64;
  const int aRow0 = (wm*64 + frow)*128;
  const int bRow0 = (wn*32 + frow)*128;

  #define STAGE_A(tau, h, bfi) do { \
    const int kk_ = (tau) >> 3; \
    const int cb_ = ((tau) & 7) << 7; \
    _Pragma("unroll") \
    for (int it_ = 0; it_ < 2; ++it_) { \
      const int orow_ = o0 + (h)*128 + it_*64 + srow; \
      const char* src_ = WbC + (size_t)(kk_*512 + orow_)*1024 + cb_ + scol; \
      __builtin_amdgcn_global_load_lds( \
        (__attribute__((address_space(1))) void*)src_, \
        (__attribute__((address_space(3))) void*)((char*)&lds[bfi][0][0] + (h)*16384 + it_*8192 + w*1024), \
        16, 0, 0); \
    } \
  } while(0)

  #define STAGE_B(tau, h, bfi) do { \
    const int kk_ = (tau) >> 3; \
    const int cb_ = ((tau) & 7) << 7; \
    const int dy_ = kk_/3 - 1, dx_ = kk_ - (kk_/3)*3 - 1; \
    _Pragma("unroll") \
    for (int it_ = 0; it_ < 2; ++it_) { \
      const int py_ = y0 + (h)*2 + it_ + dy_ + 1; \
      const int px_ = srow + dx_ + 1; \
      const char* src_ = XmC + ((size_t)((b*66 + py_)*66 + px_))*1024 + cb_ + scol; \
      __builtin_amdgcn_global_load_lds( \
        (__attribute__((address_space(1))) void*)src_, \
        (__attribute__((address_space(3))) void*)((char*)&lds[bfi][1][0] + (h)*16384 + it_*8192 + w*1024), \
        16, 0, 0); \
    } \
  } while(0)

  f32x4 acc[8][4] = {};

  // prologue: tile0 complete + B0(1), A1(1); leave 2 half-tiles in flight
  STAGE_A(0, 0, 0); STAGE_A(0, 1, 0); STAGE_B(0, 0, 0); STAGE_B(0, 1, 0);
  STAGE_B(1, 0, 1); STAGE_A(1, 1, 1);
  VMC(4);
  __builtin_amdgcn_s_barrier();

  // phase: quadrant (MH,NH) of current tile in buf BFI; STAGE stmt; VM wait
  #define PHASE(MH, NH, BFI, VM, ...) do { \
    bf16x8 a_[4][2], b_[2][2]; \
    const char* Ab_ = (const char*)&lds[BFI][0][0]; \
    const char* Bb_ = (const char*)&lds[BFI][1][0]; \
    _Pragma("unroll") \
    for (int mi_ = 0; mi_ < 4; ++mi_) { \
      a_[mi_][0] = *(const bf16x8*)(Ab_ + aRow0 + (MH)*16384 + mi_*2048 + fk0); \
      a_[mi_][1] = *(const bf16x8*)(Ab_ + aRow0 + (MH)*16384 + mi_*2048 + fk1); \
    } \
    _Pragma("unroll") \
    for (int ni_ = 0; ni_ < 2; ++ni_) { \
      b_[ni_][0] = *(const bf16x8*)(Bb_ + bRow0 + (NH)*16384 + ni_*2048 + fk0); \
      b_[ni_][1] = *(const bf16x8*)(Bb_ + bRow0 + (NH)*16384 + ni_*2048 + fk1); \
    } \
    __VA_ARGS__; \
    __builtin_amdgcn_s_barrier(); \
    __builtin_amdgcn_s_setprio(1); \
    _Pragma("unroll") \
    for (int mi_ = 0; mi_ < 4; ++mi_) \
      _Pragma("unroll") \
      for (int ni_ = 0; ni_ < 2; ++ni_) { \
        acc[(MH)*4+mi_][(NH)*2+ni_] = __builtin_amdgcn_mfma_f32_16x16x32_bf16( \
            a_[mi_][0], b_[ni_][0], acc[(MH)*4+mi_][(NH)*2+ni_], 0, 0, 0); \
        acc[(MH)*4+mi_][(NH)*2+ni_] = __builtin_amdgcn_mfma_f32_16x16x32_bf16( \
            a_[mi_][1], b_[ni_][1], acc[(MH)*4+mi_][(NH)*2+ni_], 0, 0, 0); \
      } \
    __builtin_amdgcn_s_setprio(0); \
    VM; \
    __builtin_amdgcn_s_barrier(); \
  } while(0)

  #pragma unroll 1
  for (int tt = 0; tt < 36; ++tt) {
    const int t = tt*2;
    // tile t (buf 0): quadrants Q00,Q10,Q11,Q01
    PHASE(0, 0, 0, (void)0, STAGE_A(t+1, 0, 1));
    PHASE(1, 0, 0, VMC(8),  STAGE_B(t+1, 1, 1));
    PHASE(1, 1, 0, (void)0, if (t+2 < 72) STAGE_B(t+2, 0, 0));
    PHASE(0, 1, 0, VMC(6),  if (t+2 < 72) STAGE_A(t+2, 1, 0));
    // tile t+1 (buf 1)
    PHASE(0, 0, 1, (void)0, if (t+2 < 72) STAGE_A(t+2, 0, 0));
    PHASE(1, 0, 1, VMC(8),  if (t+2 < 72) STAGE_B(t+2, 1, 0));
    PHASE(1, 1, 1, (void)0, if (t+3 < 72) STAGE_B(t+3, 0, 1));
    PHASE(0, 1, 1, VMC(6),  if (t+3 < 72) STAGE_A(t+3, 1, 1));
  }

  // epilogue: demod scale, NCHW fp32 store
  #pragma unroll
  for (int m = 0; m < 8; ++m) {
    const int o = o0 + wm*64 + (m >> 2)*128 + (m & 3)*16 + ((l >> 4) << 2);
    const f32x4 dm = *(const f32x4*)(demod + b*512 + o);
    #pragma unroll
    for (int n = 0; n < 4; ++n) {
      const int nc = wn*32 + (n >> 1)*128 + (n & 1)*16 + (l & 15);
      const int y = y0 + (nc >> 6), xx = nc & 63;
      float* op = out + (size_t)(b*512 + o)*4096 + y*64 + xx;
      #pragma unroll
      for (int r = 0; r < 4; ++r)
        op[(size_t)r*4096] = acc[m][n][r]*dm[r];
    }
  }
  #undef PHASE
  #undef STAGE_A
  #undef STAGE_B
}

// ---------------------------------------------------------------------------
extern "C" void kernel_launch(void* const* d_in, const int* in_sizes, int n_in,
                              void* d_out, int out_size, void* d_ws, size_t ws_size,
                              hipStream_t stream)
{
  const float* x      = (const float*)d_in[0];
  const float* style  = (const float*)d_in[1];
  const float* weight = (const float*)d_in[2];
  const float* mod_w  = (const float*)d_in[3];
  const float* mod_b  = (const float*)d_in[4];
  float* out = (float*)d_out;

  char* ws = (char*)d_ws;
  float* s            = (float*)(ws);                  //  32 KB  [16][512]
  float* demod        = (float*)(ws + 32768);          //  32 KB  [16][512]
  float* w2           = (float*)(ws + 65536);          //   1 MB  [512][512]
  __hip_bfloat16* Wb  = (__hip_bfloat16*)(ws + 1114112);   // 4.5 MB [9][512][512]
  __hip_bfloat16* Xm  = (__hip_bfloat16*)(ws + 5832704);   // 71.4 MB [16][66][66][512]

  hipMemsetAsync(Xm, 0, (size_t)16*66*66*512*2, stream);

  k_style <<<16,    512, 0, stream>>>(style, mod_w, mod_b, s);
  k_weight<<<512,   256, 0, stream>>>(weight, w2, Wb);
  k_demod <<<16,    256, 0, stream>>>(s, w2, demod);
  k_xm    <<<16384, 256, 0, stream>>>(x, s, Xm);
  k_conv  <<<512,   512, 0, stream>>>(Wb, Xm, demod, out);
}

// Round 3
// 397.098 us; speedup vs baseline: 1.2946x; 1.0907x over previous
//
#include <hip/hip_runtime.h>
#include <hip/hip_bf16.h>
#include <cstdint>
#include <cstddef>

typedef __bf16 bf16x8 __attribute__((ext_vector_type(8)));
typedef float f32x4 __attribute__((ext_vector_type(4)));

#define MOD_SCALE 1.4731391e-02f   // 1/sqrt(512*9)
#define EPSF 1e-8f

// ---------------------------------------------------------------------------
// K1: s[b][i] = dot(style[b], mod_w[i]) + mod_b[i]
// ---------------------------------------------------------------------------
__global__ __launch_bounds__(512) void k_style(
    const float* __restrict__ style, const float* __restrict__ mod_w,
    const float* __restrict__ mod_b, float* __restrict__ s)
{
  __shared__ float st[512];
  const int b = blockIdx.x, i = threadIdx.x;
  st[i] = style[b*512 + i];
  __syncthreads();
  const float4* mw = (const float4*)(mod_w + (size_t)i*512);
  float acc = 0.f;
  #pragma unroll 8
  for (int j = 0; j < 128; ++j) {
    float4 v = mw[j];
    acc += v.x*st[4*j] + v.y*st[4*j+1] + v.z*st[4*j+2] + v.w*st[4*j+3];
  }
  s[b*512 + i] = acc + mod_b[i];
}

// ---------------------------------------------------------------------------
// K2: w2[o][i] = sum_kk weight^2 ; Wb[kk][o][i] = bf16(SCALE*weight)
// ---------------------------------------------------------------------------
__global__ __launch_bounds__(256) void k_weight(
    const float* __restrict__ weight, float* __restrict__ w2,
    __hip_bfloat16* __restrict__ Wb)
{
  const int o = blockIdx.x, t = threadIdx.x;
  #pragma unroll
  for (int h = 0; h < 2; ++h) {
    const int i = t + h*256;
    const float* wp = weight + ((size_t)o*512 + i)*9;
    float sq = 0.f;
    #pragma unroll
    for (int kk = 0; kk < 9; ++kk) {
      float v = wp[kk];
      sq += v*v;
      Wb[((size_t)kk*512 + o)*512 + i] = __float2bfloat16(v * MOD_SCALE);
    }
    w2[(size_t)o*512 + i] = sq;
  }
}

// ---------------------------------------------------------------------------
// K2b: demod[b][o] = rsqrt(SCALE^2 * sum_i s[b][i]^2 * w2[o][i] + eps)
// ---------------------------------------------------------------------------
__global__ __launch_bounds__(256) void k_demod(
    const float* __restrict__ s, const float* __restrict__ w2,
    float* __restrict__ demod)
{
  __shared__ float s2[512];
  const int b = blockIdx.x, t = threadIdx.x;
  {
    float a = s[b*512 + t];        s2[t]     = a*a;
    float c = s[b*512 + t + 256];  s2[t+256] = c*c;
  }
  __syncthreads();
  #pragma unroll
  for (int h = 0; h < 2; ++h) {
    const int o = t + h*256;
    const float4* wp = (const float4*)(w2 + (size_t)o*512);
    float acc = 0.f;
    #pragma unroll 8
    for (int j = 0; j < 128; ++j) {
      float4 v = wp[j];
      acc += v.x*s2[4*j] + v.y*s2[4*j+1] + v.z*s2[4*j+2] + v.w*s2[4*j+3];
    }
    demod[b*512 + o] = rsqrtf(MOD_SCALE*MOD_SCALE*acc + EPSF);
  }
}

// ---------------------------------------------------------------------------
// K3: Xm[b][py][px][i] = bf16(s[b][i] * x[b][i][py-1][px-1])  (interior only;
//     halo pre-zeroed by memset).  NCHW fp32 -> padded NHWC bf16 via LDS.
// ---------------------------------------------------------------------------
__global__ __launch_bounds__(256) void k_xm(
    const float* __restrict__ x, const float* __restrict__ s,
    __hip_bfloat16* __restrict__ Xm)
{
  __shared__ __hip_bfloat16 T[64][40];
  const int bid = blockIdx.x;
  const int cb = bid & 15, y = (bid >> 4) & 63, b = bid >> 10;
  const int ic0 = cb*32;
  const int t = threadIdx.x;
  const int i = t >> 3, x0 = (t & 7)*8;
  const float sv = s[b*512 + ic0 + i];
  const float4* xp = (const float4*)(x + (size_t)(b*512 + ic0 + i)*4096 + y*64 + x0);
  float4 v0 = xp[0], v1 = xp[1];
  float vals[8] = {v0.x, v0.y, v0.z, v0.w, v1.x, v1.y, v1.z, v1.w};
  #pragma unroll
  for (int j = 0; j < 8; ++j) T[x0+j][i] = __float2bfloat16(vals[j]*sv);
  __syncthreads();
  const int p = t >> 2, c = (t & 3)*8;
  __hip_bfloat16* dst = Xm + (((size_t)(b*66 + (y+1))*66 + (p+1))*512 + ic0 + c);
  *(float4*)dst = *(const float4*)&T[p][c];
}

// ---------------------------------------------------------------------------
// K4: conv as implicit GEMM, 256x256 8-phase schedule (T1+T2+T3+T4+T5)
// with cross-phase operand register reuse (32 ds_read_b128 / K-tile / wave).
// M=512 (o, 2 tiles), N=4096 (spatial), K=72x64 (9 taps x 8 ch-chunks).
// 8 waves (2M x 4N), wave tile 128x64, acc[8][4] f32x4.
// LDS 128 KiB: [buf][A/B][256 rows][64ch], col byte ^= ((row&7)<<4) swizzle.
// ---------------------------------------------------------------------------
#define VMC(n) asm volatile("s_waitcnt vmcnt(" #n ")" ::: "memory")

__global__ __launch_bounds__(512, 2) void k_conv(
    const __hip_bfloat16* __restrict__ Wb,   // [9][512][512]
    const __hip_bfloat16* __restrict__ Xm,   // [16][66][66][512]
    const float* __restrict__ demod,         // [16][512]
    float* __restrict__ out)                 // [16][512][64][64]
{
  __shared__ __hip_bfloat16 lds[2][2][16384];   // [buf][A=0/B=1][256*64]

  const int orig = blockIdx.x;
  const int swz = (orig & 7)*64 + (orig >> 3);   // bijective XCD swizzle (512%8==0)
  const int b  = swz >> 5;
  const int nt = (swz & 31) >> 1;
  const int mt = swz & 1;
  const int o0 = mt*256, y0 = nt*4;

  const int tid = threadIdx.x;
  const int l = tid & 63;
  const int w = tid >> 6;
  const int wm = w >> 2;       // 0..1
  const int wn = w & 3;        // 0..3

  // staging per-thread constants (linear LDS dest; inverse-swizzled source)
  const int srow = tid >> 3;                                  // 0..63
  const int scol = ((tid & 7) << 4) ^ ((srow & 7) << 4);      // src col byte
  const char* WbC = (const char*)Wb;
  const char* XmC = (const char*)Xm;

  // frag-read per-lane constants (swizzled ds_read col)
  const int frow = l & 15;
  const int fk0 = ((l >> 4) << 4) ^ ((l & 7) << 4);
  const int fk1 = fk0 ^ 64;
  const int aRow0 = (wm*64 + frow)*128;
  const int bRow0 = (wn*32 + frow)*128;

  #define STAGE_A(tau, h, bfi) do { \
    const int kk_ = (tau) >> 3; \
    const int cb_ = ((tau) & 7) << 7; \
    _Pragma("unroll") \
    for (int it_ = 0; it_ < 2; ++it_) { \
      const int orow_ = o0 + (h)*128 + it_*64 + srow; \
      const char* src_ = WbC + (size_t)(kk_*512 + orow_)*1024 + cb_ + scol; \
      __builtin_amdgcn_global_load_lds( \
        (__attribute__((address_space(1))) void*)src_, \
        (__attribute__((address_space(3))) void*)((char*)&lds[bfi][0][0] + (h)*16384 + it_*8192 + w*1024), \
        16, 0, 0); \
    } \
  } while(0)

  #define STAGE_B(tau, h, bfi) do { \
    const int kk_ = (tau) >> 3; \
    const int cb_ = ((tau) & 7) << 7; \
    const int dy_ = kk_/3 - 1, dx_ = kk_ - (kk_/3)*3 - 1; \
    _Pragma("unroll") \
    for (int it_ = 0; it_ < 2; ++it_) { \
      const int py_ = y0 + (h)*2 + it_ + dy_ + 1; \
      const int px_ = srow + dx_ + 1; \
      const char* src_ = XmC + ((size_t)((b*66 + py_)*66 + px_))*1024 + cb_ + scol; \
      __builtin_amdgcn_global_load_lds( \
        (__attribute__((address_space(1))) void*)src_, \
        (__attribute__((address_space(3))) void*)((char*)&lds[bfi][1][0] + (h)*16384 + it_*8192 + w*1024), \
        16, 0, 0); \
    } \
  } while(0)

  #define RD_A(Ab, MH) do { \
    _Pragma("unroll") \
    for (int mi_ = 0; mi_ < 4; ++mi_) { \
      a_[mi_][0] = *(const bf16x8*)((Ab) + aRow0 + (MH)*16384 + mi_*2048 + fk0); \
      a_[mi_][1] = *(const bf16x8*)((Ab) + aRow0 + (MH)*16384 + mi_*2048 + fk1); \
    } \
  } while(0)

  #define RD_B(Bb, NH) do { \
    _Pragma("unroll") \
    for (int ni_ = 0; ni_ < 2; ++ni_) { \
      b_[ni_][0] = *(const bf16x8*)((Bb) + bRow0 + (NH)*16384 + ni_*2048 + fk0); \
      b_[ni_][1] = *(const bf16x8*)((Bb) + bRow0 + (NH)*16384 + ni_*2048 + fk1); \
    } \
  } while(0)

  #define MFMAQ(MH, NH) do { \
    _Pragma("unroll") \
    for (int mi_ = 0; mi_ < 4; ++mi_) \
      _Pragma("unroll") \
      for (int ni_ = 0; ni_ < 2; ++ni_) { \
        acc[(MH)*4+mi_][(NH)*2+ni_] = __builtin_amdgcn_mfma_f32_16x16x32_bf16( \
            a_[mi_][0], b_[ni_][0], acc[(MH)*4+mi_][(NH)*2+ni_], 0, 0, 0); \
        acc[(MH)*4+mi_][(NH)*2+ni_] = __builtin_amdgcn_mfma_f32_16x16x32_bf16( \
            a_[mi_][1], b_[ni_][1], acc[(MH)*4+mi_][(NH)*2+ni_], 0, 0, 0); \
      } \
  } while(0)

  // One K-tile = 4 phases, order Q00 -> Q10 -> Q11 -> Q01.
  // Register holds: b0 (P1->P2), a1 (P2->P3), b1 (P3->P4); a0 re-read at P4.
  // Staging/VMC schedule identical to the verified R2 layout.
  #define TILE(BFI, S1, S2, S3, S4, VM2, VM4) do { \
    const char* Ab_ = (const char*)&lds[BFI][0][0]; \
    const char* Bb_ = (const char*)&lds[BFI][1][0]; \
    bf16x8 a_[4][2], b_[2][2]; \
    /* P1: Q00 — read a0, b0 */ \
    RD_A(Ab_, 0); RD_B(Bb_, 0); \
    S1; \
    __builtin_amdgcn_s_barrier(); \
    __builtin_amdgcn_s_setprio(1); MFMAQ(0, 0); __builtin_amdgcn_s_setprio(0); \
    __builtin_amdgcn_s_barrier(); \
    /* P2: Q10 — read a1, reuse b0 */ \
    RD_A(Ab_, 1); \
    S2; \
    __builtin_amdgcn_s_barrier(); \
    __builtin_amdgcn_s_setprio(1); MFMAQ(1, 0); __builtin_amdgcn_s_setprio(0); \
    VM2; \
    __builtin_amdgcn_s_barrier(); \
    /* P3: Q11 — read b1, reuse a1 */ \
    RD_B(Bb_, 1); \
    S3; \
    __builtin_amdgcn_s_barrier(); \
    __builtin_amdgcn_s_setprio(1); MFMAQ(1, 1); __builtin_amdgcn_s_setprio(0); \
    __builtin_amdgcn_s_barrier(); \
    /* P4: Q01 — re-read a0, reuse b1 */ \
    RD_A(Ab_, 0); \
    S4; \
    __builtin_amdgcn_s_barrier(); \
    __builtin_amdgcn_s_setprio(1); MFMAQ(0, 1); __builtin_amdgcn_s_setprio(0); \
    VM4; \
    __builtin_amdgcn_s_barrier(); \
  } while(0)

  f32x4 acc[8][4] = {};

  // prologue: tile0 complete + B0(1), A1(1); leave 2 half-tiles in flight
  STAGE_A(0, 0, 0); STAGE_A(0, 1, 0); STAGE_B(0, 0, 0); STAGE_B(0, 1, 0);
  STAGE_B(1, 0, 1); STAGE_A(1, 1, 1);
  VMC(4);
  __builtin_amdgcn_s_barrier();

  #pragma unroll 1
  for (int tt = 0; tt < 35; ++tt) {
    const int t = tt*2;
    TILE(0, STAGE_A(t+1,0,1), STAGE_B(t+1,1,1), STAGE_B(t+2,0,0), STAGE_A(t+2,1,0),
            VMC(8), VMC(6));
    TILE(1, STAGE_A(t+2,0,0), STAGE_B(t+2,1,0), STAGE_B(t+3,0,1), STAGE_A(t+3,1,1),
            VMC(8), VMC(6));
  }
  // tail: t = 70 — no further stages; tightened waits cover remaining reads
  TILE(0, STAGE_A(71,0,1), STAGE_B(71,1,1), (void)0, (void)0, VMC(8), VMC(2));
  TILE(1, (void)0, (void)0, (void)0, (void)0, VMC(0), (void)0);

  // epilogue: demod scale, NCHW fp32 store
  #pragma unroll
  for (int m = 0; m < 8; ++m) {
    const int o = o0 + wm*64 + (m >> 2)*128 + (m & 3)*16 + ((l >> 4) << 2);
    const f32x4 dm = *(const f32x4*)(demod + b*512 + o);
    #pragma unroll
    for (int n = 0; n < 4; ++n) {
      const int nc = wn*32 + (n >> 1)*128 + (n & 1)*16 + (l & 15);
      const int y = y0 + (nc >> 6), xx = nc & 63;
      float* op = out + (size_t)(b*512 + o)*4096 + y*64 + xx;
      #pragma unroll
      for (int r = 0; r < 4; ++r)
        op[(size_t)r*4096] = acc[m][n][r]*dm[r];
    }
  }
  #undef TILE
  #undef MFMAQ
  #undef RD_A
  #undef RD_B
  #undef STAGE_A
  #undef STAGE_B
}

// ---------------------------------------------------------------------------
extern "C" void kernel_launch(void* const* d_in, const int* in_sizes, int n_in,
                              void* d_out, int out_size, void* d_ws, size_t ws_size,
                              hipStream_t stream)
{
  const float* x      = (const float*)d_in[0];
  const float* style  = (const float*)d_in[1];
  const float* weight = (const float*)d_in[2];
  const float* mod_w  = (const float*)d_in[3];
  const float* mod_b  = (const float*)d_in[4];
  float* out = (float*)d_out;

  char* ws = (char*)d_ws;
  float* s            = (float*)(ws);                  //  32 KB  [16][512]
  float* demod        = (float*)(ws + 32768);          //  32 KB  [16][512]
  float* w2           = (float*)(ws + 65536);          //   1 MB  [512][512]
  __hip_bfloat16* Wb  = (__hip_bfloat16*)(ws + 1114112);   // 4.5 MB [9][512][512]
  __hip_bfloat16* Xm  = (__hip_bfloat16*)(ws + 5832704);   // 71.4 MB [16][66][66][512]

  hipMemsetAsync(Xm, 0, (size_t)16*66*66*512*2, stream);

  k_style <<<16,    512, 0, stream>>>(style, mod_w, mod_b, s);
  k_weight<<<512,   256, 0, stream>>>(weight, w2, Wb);
  k_demod <<<16,    256, 0, stream>>>(s, w2, demod);
  k_xm    <<<16384, 256, 0, stream>>>(x, s, Xm);
  k_conv  <<<512,   512, 0, stream>>>(Wb, Xm, demod, out);
}